// Round 1
// baseline (1251.443 us; speedup 1.0000x reference)
//
#include <hip/hip_runtime.h>
#include <cstddef>

// Problem constants
#define NB   1024
#define CIN  384
#define NPIX 361      // 19*19
#define CP   48       // p channels
#define CG   48       // g channels
#define NCH  96       // CP + CG
#define TILE 128      // pixels per block in K1
#define KC   64       // k-chunk
#define WSTR 100      // padded LDS stride for W chunk [KC][96] (100%32=4 -> spread banks, 400B rows keep 16B align)

// LDS plan (floats): xs[0..8192) = x chunk [KC][TILE]; wl[8192..14592) = W chunk [KC][WSTR]
// epilogue reuse:    gsum[0..6336) [48][132], gmax[6336..12672), ps[12672..12864), pm[12864..13056)
#define SMEM_F 14592

__global__ __launch_bounds__(256) void k1_conv1_pool(
    const float* __restrict__ x, const float* __restrict__ mask,
    const float* __restrict__ w1p, const float* __restrict__ w1g,
    const float* __restrict__ betag,
    float* __restrict__ outp, float* __restrict__ psum, float* __restrict__ pmax)
{
    __shared__ float smem[SMEM_F];
    float* xs = smem;
    float* wl = smem + 8192;

    const int n  = blockIdx.x;
    const int t  = blockIdx.y;          // 0..2, pixel tile
    const int l0 = t * TILE;
    const int tid  = threadIdx.x;
    const int lane = tid & 63;
    const int wv   = tid >> 6;          // 0..3
    const int chbase = wv * 24;         // wv0,1 -> p ch 0..47 ; wv2,3 -> g ch 0..47

    float acc0[24], acc1[24];
    #pragma unroll
    for (int j = 0; j < 24; ++j) { acc0[j] = 0.f; acc1[j] = 0.f; }

    const float* xn = x + (size_t)n * CIN * NPIX;

    for (int ck = 0; ck < CIN; ck += KC) {
        // stage x chunk: [KC][TILE], coalesced over pixels
        #pragma unroll
        for (int i = 0; i < (KC * TILE / 256); ++i) {     // 32
            int e = tid + 256 * i;
            int c = e >> 7;            // 0..63
            int p = e & 127;
            int gp = l0 + p;
            xs[e] = (gp < NPIX) ? xn[(size_t)(ck + c) * NPIX + gp] : 0.f;
        }
        // stage W chunk: global coalesced along c, LDS layout wl[c][ch] (stride WSTR)
        #pragma unroll
        for (int i = 0; i < (KC * NCH / 256); ++i) {      // 24
            int e = tid + 256 * i;
            int ch = e >> 6;           // 0..95, wave-uniform
            int c  = e & 63;
            float v = (ch < CP) ? w1p[ch * CIN + ck + c]
                                : w1g[(ch - CP) * CIN + ck + c];
            wl[c * WSTR + ch] = v;
        }
        __syncthreads();

        #pragma unroll 2
        for (int c = 0; c < KC; ++c) {
            float xv0 = xs[c * TILE + lane];
            float xv1 = xs[c * TILE + 64 + lane];
            const float4* w4 = reinterpret_cast<const float4*>(wl + c * WSTR + chbase);
            #pragma unroll
            for (int q = 0; q < 6; ++q) {
                float4 w = w4[q];
                acc0[q*4+0] += w.x * xv0;  acc1[q*4+0] += w.x * xv1;
                acc0[q*4+1] += w.y * xv0;  acc1[q*4+1] += w.y * xv1;
                acc0[q*4+2] += w.z * xv0;  acc1[q*4+2] += w.z * xv1;
                acc0[q*4+3] += w.w * xv0;  acc1[q*4+3] += w.w * xv1;
            }
        }
        __syncthreads();
    }

    const int p0 = l0 + lane;
    const int p1 = l0 + 64 + lane;
    const bool v0ok = p0 < NPIX;
    const bool v1ok = p1 < NPIX;

    if (wv < 2) {
        // p channels: store pre-activation outp to workspace (coalesced per channel row)
        float* op = outp + ((size_t)n * CP + chbase) * NPIX;
        #pragma unroll
        for (int j = 0; j < 24; ++j) {
            if (v0ok) op[(size_t)j * NPIX + p0] = acc0[j];
            if (v1ok) op[(size_t)j * NPIX + p1] = acc1[j];
        }
    } else {
        // g channels: relu((acc+beta)*mask), write sum/max candidates into LDS
        const float* mn = mask + (size_t)n * NPIX;
        float m0 = v0ok ? mn[p0] : 0.f;
        float m1 = v1ok ? mn[p1] : 0.f;
        float* gsum = smem;
        float* gmax = smem + 6336;
        #pragma unroll
        for (int j = 0; j < 24; ++j) {
            int gch = chbase - CP + j;   // 0..47
            float b = betag[gch];
            float r0 = fmaxf((acc0[j] + b) * m0, 0.f);
            float r1 = fmaxf((acc1[j] + b) * m1, 0.f);
            gsum[gch * 132 + lane]      = v0ok ? r0 : 0.f;
            gsum[gch * 132 + 64 + lane] = v1ok ? r1 : 0.f;
            gmax[gch * 132 + lane]      = v0ok ? (r0 + (m0 - 1.f)) : -1e30f;
            gmax[gch * 132 + 64 + lane] = v1ok ? (r1 + (m1 - 1.f)) : -1e30f;
        }
    }
    __syncthreads();

    // reduce 128 pixel columns -> per (n,t) partials
    {
        int ch = tid >> 2;
        int q  = tid & 3;
        if (ch < CG) {
            const float* gsum = smem;
            const float* gmax = smem + 6336;
            float s = 0.f, mx = -1e30f;
            #pragma unroll
            for (int i = 0; i < 32; ++i) {
                int idx = ch * 132 + q * 32 + i;
                s += gsum[idx];
                mx = fmaxf(mx, gmax[idx]);
            }
            smem[12672 + ch * 4 + q] = s;
            smem[12864 + ch * 4 + q] = mx;
        }
    }
    __syncthreads();
    if (tid < CG) {
        float s  = smem[12672 + tid*4] + smem[12672 + tid*4 + 1]
                 + smem[12672 + tid*4 + 2] + smem[12672 + tid*4 + 3];
        float mx = fmaxf(fmaxf(smem[12864 + tid*4],     smem[12864 + tid*4 + 1]),
                         fmaxf(smem[12864 + tid*4 + 2], smem[12864 + tid*4 + 3]));
        psum[((size_t)n * 3 + t) * CG + tid] = s;
        pmax[((size_t)n * 3 + t) * CG + tid] = mx;
    }
}

__global__ __launch_bounds__(64) void k2_pool_linears(
    const float* __restrict__ psum, const float* __restrict__ pmax,
    const float* __restrict__ mask_sum,
    const float* __restrict__ wlg, const float* __restrict__ wlp,
    const float* __restrict__ blp, const float* __restrict__ wlp2,
    float* __restrict__ glin, float* __restrict__ out)
{
    __shared__ float gp[3 * CG];
    __shared__ float hbuf[CP];
    const int n = blockIdx.x;
    const int tid = threadIdx.x;

    if (tid < CG) {
        float s  = psum[((size_t)n*3 + 0)*CG + tid] + psum[((size_t)n*3 + 1)*CG + tid]
                 + psum[((size_t)n*3 + 2)*CG + tid];
        float mx = fmaxf(fmaxf(pmax[((size_t)n*3 + 0)*CG + tid],
                               pmax[((size_t)n*3 + 1)*CG + tid]),
                               pmax[((size_t)n*3 + 2)*CG + tid]);
        float ms = mask_sum[n];
        float mean = s / ms;
        float offset = sqrtf(ms) - 14.0f;
        gp[tid]        = mean;
        gp[CG + tid]   = mean * (offset * 0.1f);
        gp[2*CG + tid] = mx;
    }
    __syncthreads();
    if (tid < CP) {
        float h = blp[tid];
        float gl = 0.f;
        #pragma unroll 4
        for (int k = 0; k < 3*CG; ++k) {
            float g = gp[k];
            h  += g * wlp[tid * (3*CG) + k];
            gl += g * wlg[tid * (3*CG) + k];
        }
        h = fmaxf(h, 0.f);
        hbuf[tid] = h;
        glin[(size_t)n * CP + tid] = gl;
    }
    __syncthreads();
    if (tid < 2) {
        float o = 0.f;
        #pragma unroll
        for (int j = 0; j < CP; ++j) o += hbuf[j] * wlp2[tid * CP + j];
        out[((size_t)n * 6 + (tid ? 5 : 0)) * 362 + 361] = o;
    }
}

__global__ __launch_bounds__(256) void k3_epilogue(
    const float* __restrict__ outp, const float* __restrict__ glin,
    const float* __restrict__ mask, const float* __restrict__ beta2,
    const float* __restrict__ w2, float* __restrict__ out)
{
    int gid = blockIdx.x * 256 + threadIdx.x;
    if (gid >= NB * NPIX) return;
    int n = gid / NPIX;
    int pix = gid - n * NPIX;
    float m = mask[(size_t)n * NPIX + pix];
    const float* op = outp + (size_t)n * CP * NPIX + pix;
    const float* gl = glin + (size_t)n * CP;
    float o0 = 0.f, o1 = 0.f;
    #pragma unroll 8
    for (int c = 0; c < CP; ++c) {
        float v = fmaxf((op[(size_t)c * NPIX] + gl[c] + beta2[c]) * m, 0.f);
        o0 += w2[c] * v;
        o1 += w2[CP + c] * v;
    }
    float pen = (1.f - m) * 5000.f;
    out[((size_t)n * 6 + 0) * 362 + pix] = o0 - pen;
    out[((size_t)n * 6 + 5) * 362 + pix] = o1 - pen;
}

extern "C" void kernel_launch(void* const* d_in, const int* in_sizes, int n_in,
                              void* d_out, int out_size, void* d_ws, size_t ws_size,
                              hipStream_t stream) {
    const float* x     = (const float*)d_in[0];
    const float* mask  = (const float*)d_in[1];
    const float* msum  = (const float*)d_in[2];
    const float* w1p   = (const float*)d_in[3];
    const float* w1g   = (const float*)d_in[4];
    const float* betag = (const float*)d_in[5];
    const float* wlg   = (const float*)d_in[6];
    const float* wlp   = (const float*)d_in[7];
    const float* blp   = (const float*)d_in[8];
    const float* wlp2  = (const float*)d_in[9];
    const float* beta2 = (const float*)d_in[10];
    const float* w2    = (const float*)d_in[11];
    float* out = (float*)d_out;

    float* ws    = (float*)d_ws;
    float* wsOutp = ws;                                     // 1024*48*361
    float* psum  = ws + (size_t)NB * CP * NPIX;             // 1024*3*48
    float* pmax  = psum + (size_t)NB * 3 * CG;              // 1024*3*48
    float* glin  = pmax + (size_t)NB * 3 * CG;              // 1024*48

    // channels 1..4 (and all untouched slots) must be zero; harness re-poisons d_out
    hipMemsetAsync(d_out, 0, (size_t)NB * 6 * 362 * sizeof(float), stream);

    dim3 g1(NB, 3);
    k1_conv1_pool<<<g1, 256, 0, stream>>>(x, mask, w1p, w1g, betag, wsOutp, psum, pmax);
    k2_pool_linears<<<NB, 64, 0, stream>>>(psum, pmax, msum, wlg, wlp, blp, wlp2, glin, out);
    k3_epilogue<<<(NB * NPIX) / 256, 256, 0, stream>>>(wsOutp, glin, mask, beta2, w2, out);
}